// Round 3
// baseline (119.040 us; speedup 1.0000x reference)
//
#include <hip/hip_runtime.h>
#include <stdint.h>

typedef __attribute__((ext_vector_type(8))) short short8;
typedef __attribute__((ext_vector_type(4))) float f32x4;
typedef unsigned short ushort_t;

// fp32 -> bf16 round-to-nearest-even
__device__ __forceinline__ ushort_t f2bf(float f) {
  uint32_t u = __float_as_uint(f);
  u += 0x7fffu + ((u >> 16) & 1u);
  return (ushort_t)(u >> 16);
}

__device__ __forceinline__ uint2 pack4(float4 v) {
  return make_uint2((uint32_t)f2bf(v.x) | ((uint32_t)f2bf(v.y) << 16),
                    (uint32_t)f2bf(v.z) | ((uint32_t)f2bf(v.w) << 16));
}

// async global->LDS, 16B per lane; LDS dest = wave-uniform base + lane*16
__device__ __forceinline__ void load_lds16(const ushort_t* g, ushort_t* l) {
  __builtin_amdgcn_global_load_lds(
      (const __attribute__((address_space(1))) uint32_t*)g,
      (__attribute__((address_space(3))) uint32_t*)l, 16, 0, 0);
}

// --- K1: per-row deg -> dis, write (A + I) as bf16. One wave per row. -------
__global__ __launch_bounds__(256) void k_prep(const float4* __restrict__ A4,
                                              ushort_t* __restrict__ Abf,
                                              float* __restrict__ dis) {
  const int tid = threadIdx.x;
  const int row = blockIdx.x * 4 + (tid >> 6);  // b*512 + n
  const int lane = tid & 63;
  const int n = row & 511;
  const float4* src = A4 + (size_t)row * 128;
  uint2* dst = (uint2*)(Abf + (size_t)row * 512);
  float s = 0.0f;
#pragma unroll
  for (int i = 0; i < 2; ++i) {
    const int idx = i * 64 + lane;
    float4 v = src[idx];
    const int c0 = idx * 4;
    v.x += (float)(c0 == n);  // fold identity into the bf16 copy
    v.y += (float)(c0 + 1 == n);
    v.z += (float)(c0 + 2 == n);
    v.w += (float)(c0 + 3 == n);
    s += (v.x + v.y) + (v.z + v.w);
    dst[idx] = pack4(v);
  }
#pragma unroll
  for (int off = 32; off > 0; off >>= 1) s += __shfl_down(s, off, 64);
  if (lane == 0) dis[row] = rsqrtf(s + 1e-8f);
}

// --- K2: Gt[b][o][m] = (sum_i W[o,i]*H[b,m,i] + bias[o]) * dis[b,m] ---------
// tile 64(o) x 128(m), K=256, BK=32. H and W read as fp32, converted to bf16
// in a reg->pack->ds_write staging pipeline (no Hbf/Wbf intermediates).
__global__ __launch_bounds__(256) void k_gemm_gt(
    const float* __restrict__ W,     // [256][256] fp32
    const float* __restrict__ H,     // [32][512][256] fp32
    const float* __restrict__ bias,  // [256]
    const float* __restrict__ dis,   // [32*512]
    ushort_t* __restrict__ Gt) {     // [32][256][512] bf16
  __shared__ ushort_t As[2][64 * 32];   // W rows  (o x k)
  __shared__ ushort_t Bs[2][128 * 32];  // H rows  (m x k)
  const int bid = blockIdx.x;
  const int yo = bid >> 7;    // o-tile 0..3
  const int rr = bid & 127;
  const int batch = rr >> 2;  // 0..31
  const int xm = rr & 3;      // m-tile 0..3
  const int ot0 = yo * 64, mt0 = xm * 128;
  const int tid = threadIdx.x, lane = tid & 63, wv = tid >> 6;
  const int wo = wv & 1;    // o half (2 x 32)
  const int wmh = wv >> 1;  // m half (2 x 64)
  const int lr = lane & 15, q = lane >> 4;
  const float* Hb = H + (size_t)batch * 512 * 256;

  // staging geometry (fp32 inline convert)
  const int a_r = tid >> 2, a_kc = (tid & 3) * 8;    // W: 64 rows x 4 chunks
  const int b_r = tid >> 1, b_kc = (tid & 1) * 16;   // H: 128 rows x 2 chunks

  f32x4 acc[2][4];
#pragma unroll
  for (int i = 0; i < 2; ++i)
#pragma unroll
    for (int j = 0; j < 4; ++j) acc[i][j] = {0.f, 0.f, 0.f, 0.f};

  float4 ra[2], rb[4];
  auto gload = [&](int k0) {
    const float* wp = W + (size_t)(ot0 + a_r) * 256 + k0 + a_kc;
    ra[0] = *(const float4*)wp;
    ra[1] = *(const float4*)(wp + 4);
    const float* hp = Hb + (size_t)(mt0 + b_r) * 256 + k0 + b_kc;
#pragma unroll
    for (int j = 0; j < 4; ++j) rb[j] = *(const float4*)(hp + 4 * j);
  };
  auto stash = [&](int p) {
    uint2 a0 = pack4(ra[0]), a1 = pack4(ra[1]);
    *(uint4*)&As[p][a_r * 32 + a_kc] = make_uint4(a0.x, a0.y, a1.x, a1.y);
    uint2 b0 = pack4(rb[0]), b1 = pack4(rb[1]);
    uint2 b2 = pack4(rb[2]), b3 = pack4(rb[3]);
    *(uint4*)&Bs[p][b_r * 32 + b_kc] = make_uint4(b0.x, b0.y, b1.x, b1.y);
    *(uint4*)&Bs[p][b_r * 32 + b_kc + 8] = make_uint4(b2.x, b2.y, b3.x, b3.y);
  };
  auto compute = [&](int p) {
    short8 af[2], bfr[4];
#pragma unroll
    for (int mt = 0; mt < 2; ++mt)
      af[mt] = *(const short8*)&As[p][(wo * 32 + mt * 16 + lr) * 32 + q * 8];
#pragma unroll
    for (int nt = 0; nt < 4; ++nt)
      bfr[nt] = *(const short8*)&Bs[p][(wmh * 64 + nt * 16 + lr) * 32 + q * 8];
#pragma unroll
    for (int mt = 0; mt < 2; ++mt)
#pragma unroll
      for (int nt = 0; nt < 4; ++nt)
        acc[mt][nt] = __builtin_amdgcn_mfma_f32_16x16x32_bf16(
            af[mt], bfr[nt], acc[mt][nt], 0, 0, 0);
  };

  gload(0);
#pragma unroll
  for (int it = 0; it < 8; ++it) {
    stash(it & 1);
    __syncthreads();
    if (it + 1 < 8) gload((it + 1) * 32);  // in flight across compute
    compute(it & 1);
  }

  float dm[4];
#pragma unroll
  for (int nt = 0; nt < 4; ++nt)
    dm[nt] = dis[batch * 512 + mt0 + wmh * 64 + nt * 16 + lr];
#pragma unroll
  for (int mt = 0; mt < 2; ++mt) {
    const int ob = ot0 + wo * 32 + mt * 16 + q * 4;
    float bs[4];
#pragma unroll
    for (int r = 0; r < 4; ++r) bs[r] = bias[ob + r];
#pragma unroll
    for (int nt = 0; nt < 4; ++nt) {
      const int m = mt0 + wmh * 64 + nt * 16 + lr;
      ushort_t* dstp = Gt + ((size_t)batch * 256 + ob) * 512 + m;
#pragma unroll
      for (int r = 0; r < 4; ++r)
        dstp[(size_t)r * 512] = f2bf((acc[mt][nt][r] + bs[r]) * dm[nt]);
    }
  }
}

// --- K3: out[b][n][o] = relu( (Ahat @ G)[n,o] * dis[b,n] * mask[b,n] ) ------
// tile 64(n) x 64(o), K=512, BK=32; grid 1024 = 4 blocks/CU for latency
// hiding. bid = yo*256 + batch*8 + xn -> Ahat-tile sharers land on one XCD.
__global__ __launch_bounds__(256, 4) void k_gemm_out(
    const ushort_t* __restrict__ Abf,  // [32][512][512] (A + I) bf16
    const ushort_t* __restrict__ Gt,   // [32][256][512] bf16
    const float* __restrict__ dis,     // [32*512]
    const float* __restrict__ mask,    // [32*512]
    float* __restrict__ out) {         // [32][512][256] fp32
  __shared__ ushort_t As[2][64 * 32];  // Ahat rows (n x k)
  __shared__ ushort_t Bs[2][64 * 32];  // Gt rows   (o x k)
  const int bid = blockIdx.x;
  const int yo = bid >> 8;    // o-tile 0..3
  const int rem = bid & 255;
  const int batch = rem >> 3;  // 0..31
  const int xn = rem & 7;      // n-tile 0..7
  const int nt0 = xn * 64, ot0 = yo * 64;
  const int tid = threadIdx.x, lane = tid & 63, wv = tid >> 6;
  const int wn2 = wv & 1;   // n half (2 x 32)
  const int wo2 = wv >> 1;  // o half (2 x 32)
  const int lr = lane & 15, q = lane >> 4;
  const int rstage = lane >> 2, koff = (lane & 3) * 8;
  const ushort_t* Ab = Abf + (size_t)batch * 512 * 512;
  const ushort_t* Gb = Gt + (size_t)batch * 256 * 512;

  f32x4 acc[2][2];
#pragma unroll
  for (int i = 0; i < 2; ++i)
#pragma unroll
    for (int j = 0; j < 2; ++j) acc[i][j] = {0.f, 0.f, 0.f, 0.f};

  auto stage = [&](int k0, int p) {
    load_lds16(Ab + (size_t)(nt0 + wv * 16 + rstage) * 512 + k0 + koff,
               &As[p][wv * 512]);
    load_lds16(Gb + (size_t)(ot0 + wv * 16 + rstage) * 512 + k0 + koff,
               &Bs[p][wv * 512]);
  };
  auto compute = [&](int p) {
    short8 af[2], bfr[2];
#pragma unroll
    for (int mt = 0; mt < 2; ++mt)
      af[mt] = *(const short8*)&As[p][(wn2 * 32 + mt * 16 + lr) * 32 + q * 8];
#pragma unroll
    for (int nt = 0; nt < 2; ++nt)
      bfr[nt] = *(const short8*)&Bs[p][(wo2 * 32 + nt * 16 + lr) * 32 + q * 8];
#pragma unroll
    for (int mt = 0; mt < 2; ++mt)
#pragma unroll
      for (int nt = 0; nt < 2; ++nt)
        acc[mt][nt] = __builtin_amdgcn_mfma_f32_16x16x32_bf16(
            af[mt], bfr[nt], acc[mt][nt], 0, 0, 0);
  };

  stage(0, 0);
#pragma unroll
  for (int it = 0; it < 16; ++it) {
    __syncthreads();  // tile it landed; everyone done with buf (it+1)&1
    if (it + 1 < 16) stage((it + 1) * 32, (it + 1) & 1);
    compute(it & 1);
  }

#pragma unroll
  for (int mt = 0; mt < 2; ++mt) {
    const int nb = nt0 + wn2 * 32 + mt * 16 + q * 4;
    float sc[4];
#pragma unroll
    for (int r = 0; r < 4; ++r) {
      const int gn = batch * 512 + nb + r;
      sc[r] = dis[gn] * mask[gn];
    }
#pragma unroll
    for (int nt = 0; nt < 2; ++nt) {
      const int o = ot0 + wo2 * 32 + nt * 16 + lr;
      float* dstp = out + ((size_t)(batch * 512 + nb)) * 256 + o;
#pragma unroll
      for (int r = 0; r < 4; ++r) {
        float v = acc[mt][nt][r] * sc[r];
        dstp[(size_t)r * 256] = v > 0.0f ? v : 0.0f;
      }
    }
  }
}

extern "C" void kernel_launch(void* const* d_in, const int* in_sizes, int n_in,
                              void* d_out, int out_size, void* d_ws,
                              size_t ws_size, hipStream_t stream) {
  const float* H = (const float*)d_in[0];     // [32][512][256]
  const float* A = (const float*)d_in[1];     // [32][512][512]
  const float* mask = (const float*)d_in[2];  // [32][512]
  const float* W = (const float*)d_in[3];     // [256][256]
  const float* b = (const float*)d_in[4];     // [256]
  float* out = (float*)d_out;                 // [32][512][256]

  char* ws = (char*)d_ws;
  ushort_t* Abf = (ushort_t*)ws;                   // 16 MiB
  ushort_t* Gt = (ushort_t*)(ws + 16777216);       // 8 MiB
  float* dis = (float*)(ws + 16777216 + 8388608);  // 64 KiB

  // 1) deg -> dis, (A+I) -> bf16
  k_prep<<<4096, 256, 0, stream>>>((const float4*)A, Abf, dis);
  // 2) Gt = dis * (W @ H^T + b)   [bf16, transposed; H/W fp32 inline-convert]
  k_gemm_gt<<<512, 256, 0, stream>>>(W, H, b, dis, Gt);
  // 3) out = relu(mask * dis * (Ahat @ G))
  k_gemm_out<<<1024, 256, 0, stream>>>(Abf, Gt, dis, mask, out);
}